// Round 12
// baseline (6105.040 us; speedup 1.0000x reference)
//
#include <hip/hip_runtime.h>

// ---------------------------------------------------------------------------
// DIAGNOSTIC (fixed): full fp32 pipeline (no bf16, no MFMA). Round-9 run
// exposed an s_s overflow (FFN wrote 256 cols into a 196-wide buffer);
// FFN now processes hidden in 2 halves of 128. Decides between
// "precision mechanism" (passes) and "structural logic bug" (fails ~0.13).
// ---------------------------------------------------------------------------

typedef __attribute__((ext_vector_type(4))) float f4;

__device__ __forceinline__ float dot4(f4 a, f4 b, float acc) {
  acc = fmaf(a.x, b.x, acc); acc = fmaf(a.y, b.y, acc);
  acc = fmaf(a.z, b.z, acc); acc = fmaf(a.w, b.w, acc);
  return acc;
}

// ---------------------------------------------------------------------------
__global__ __launch_bounds__(256) void moe_fp32(
    const float* __restrict__ x0, const float* __restrict__ x1, const float* __restrict__ x2,
    const float* __restrict__ gw, const float* __restrict__ gb,
    const float* __restrict__ w1, const float* __restrict__ b1,
    const float* __restrict__ w2, const float* __restrict__ b2,
    const float* __restrict__ cls, const float* __restrict__ pos,
    float* __restrict__ xtok)
{
  __shared__ float x_s[64][132];   // fp32 input rows (pad 4)
  __shared__ float h_s[64][68];    // relu'd hidden (pad 4)
  __shared__ float g_s[64][32];    // gates

  const int t = threadIdx.x, lane = t & 63, w = t >> 6;
  const int v = blockIdx.x >> 8, b0 = (blockIdx.x & 255) * 64;
  const float* xv = (v == 0 ? x0 : (v == 1 ? x1 : x2)) + (long)b0 * 128;

  // stage x (64 x 128 fp32)
#pragma unroll
  for (int i = 0; i < 8; i++) {
    int fi = t + i * 256;
    int r = fi >> 5, c4 = fi & 31;
    *(f4*)&x_s[r][c4 * 4] = *(const f4*)(xv + r * 128 + c4 * 4);
  }
  __syncthreads();

  // ---- gates (exact fp32): thread t -> sample s = t>>2, 8 experts each ----
  {
    const int s = t >> 2, q = t & 3;
    const int e0 = q * 8, ne = (q == 3) ? 6 : 8;
    float lg[8];
#pragma unroll
    for (int j = 0; j < 8; j++) lg[j] = -1e30f;
#pragma unroll
    for (int j = 0; j < 8; j++) {
      if (j < ne) {
        int e = e0 + j;
        float acc = 0.f;
#pragma unroll
        for (int k4 = 0; k4 < 32; k4++) {
          f4 xx = *(const f4*)&x_s[s][k4 * 4];
          f4 ww = *(const f4*)(gw + e * 128 + k4 * 4);
          acc = dot4(xx, ww, acc);
        }
        lg[j] = acc + gb[e];
      }
    }
    float m = lg[0];
#pragma unroll
    for (int j = 1; j < 8; j++) m = fmaxf(m, lg[j]);
    m = fmaxf(m, __shfl_xor(m, 1));
    m = fmaxf(m, __shfl_xor(m, 2));
    float p[8], ssum = 0.f;
#pragma unroll
    for (int j = 0; j < 8; j++) {
      p[j] = (j < ne) ? expf(lg[j] - m) : 0.f;
      ssum += p[j];
    }
    ssum += __shfl_xor(ssum, 1);
    ssum += __shfl_xor(ssum, 2);
    float inv = 1.f / ssum;
#pragma unroll
    for (int j = 0; j < 8; j++)
      if (j < ne) g_s[s][e0 + j] = p[j] * inv;
  }
  // g_s / h_s / x_s rows are wave-aligned from here on: no more barriers.

  // ---- expert loop: wave w owns rows 16w..16w+15; lane = output column ----
  const int row0 = 16 * w;
  float oacc[16];
#pragma unroll
  for (int r = 0; r < 16; r++) oacc[r] = 0.f;

#pragma unroll 1
  for (int e = 0; e < 30; e++) {
    // GEMM1: h[row][lane] = relu(sum_k x[row][k] * w1[e][lane][k] + b1)
    const float* w1e = w1 + (long)e * 8192 + lane * 128;
    float acc1[16];
#pragma unroll
    for (int r = 0; r < 16; r++) acc1[r] = 0.f;
#pragma unroll
    for (int kc = 0; kc < 4; kc++) {
      f4 wr[8];
#pragma unroll
      for (int k4 = 0; k4 < 8; k4++) wr[k4] = *(const f4*)(w1e + kc * 32 + k4 * 4);
#pragma unroll
      for (int r = 0; r < 16; r++)
#pragma unroll
        for (int k4 = 0; k4 < 8; k4++) {
          f4 xx = *(const f4*)&x_s[row0 + r][kc * 32 + k4 * 4];
          acc1[r] = dot4(xx, wr[k4], acc1[r]);
        }
    }
    float bb1 = b1[e * 64 + lane];
#pragma unroll
    for (int r = 0; r < 16; r++)
      h_s[row0 + r][lane] = fmaxf(acc1[r] + bb1, 0.f);

    // GEMM2: y[row][lane] = sum_h h[row][h] * w2[e][lane][h] + b2
    const float* w2e = w2 + (long)e * 4096 + lane * 64;
    float acc2[16];
#pragma unroll
    for (int r = 0; r < 16; r++) acc2[r] = 0.f;
#pragma unroll
    for (int kc = 0; kc < 2; kc++) {
      f4 wr[8];
#pragma unroll
      for (int k4 = 0; k4 < 8; k4++) wr[k4] = *(const f4*)(w2e + kc * 32 + k4 * 4);
#pragma unroll
      for (int r = 0; r < 16; r++)
#pragma unroll
        for (int k4 = 0; k4 < 8; k4++) {
          f4 hh = *(const f4*)&h_s[row0 + r][kc * 32 + k4 * 4];
          acc2[r] = dot4(hh, wr[k4], acc2[r]);
        }
    }
    float bb2 = b2[e * 64 + lane];
#pragma unroll
    for (int r = 0; r < 16; r++)
      oacc[r] += g_s[row0 + r][e] * (acc2[r] + bb2);
  }

  // ---- store tokens (fp32) + cls token ----
  float pe = pos[(v + 1) * 64 + lane];
#pragma unroll
  for (int r = 0; r < 16; r++)
    xtok[((long)(b0 + row0 + r) * 4 + (v + 1)) * 64 + lane] = oacc[r] + pe;
  if (v == 0) {
    float cv = cls[lane] + pos[lane];
#pragma unroll
    for (int r = 0; r < 16; r++)
      xtok[((long)(b0 + row0 + r) * 4) * 64 + lane] = cv;
  }
}

// ---------------------------------------------------------------------------
__global__ __launch_bounds__(256) void former_fp32(
    const float* __restrict__ qw,  const float* __restrict__ qb,
    const float* __restrict__ ow,  const float* __restrict__ ob,
    const float* __restrict__ l1g, const float* __restrict__ l1b,
    const float* __restrict__ f1w, const float* __restrict__ fb1,
    const float* __restrict__ f2w, const float* __restrict__ fb2,
    const float* __restrict__ l2g, const float* __restrict__ l2b,
    const float* __restrict__ hw,  const float* __restrict__ hb,
    const float* __restrict__ xtok,
    float* __restrict__ outp)
{
  __shared__ float x_s[4][32][68];    // residual stream (fp32, exact)
  __shared__ float s_s[4][32][196];   // QKV (192 cols) -> O (64) -> FFN half (128)

  const int t = threadIdx.x, lane = t & 63, w = t >> 6;
  const int row0 = blockIdx.x * 128 + w * 32;

  // stage x (wave-private)
#pragma unroll
  for (int i = 0; i < 8; i++) {
    int fi = lane + i * 64;
    int r = fi >> 4, c4 = fi & 15;
    *(f4*)&x_s[w][r][c4 * 4] = *(const f4*)(xtok + (long)(row0 + r) * 64 + c4 * 4);
  }

#pragma unroll 1
  for (int l = 0; l < 2; l++) {
    // ---- QKV projection: lane = col (3 passes of 64 cols) ----
#pragma unroll 1
    for (int it = 0; it < 3; it++) {
      int col = it * 64 + lane;
      const float* wrow = qw + (long)(l * 192 + col) * 64;
      f4 wr[16];
#pragma unroll
      for (int k4 = 0; k4 < 16; k4++) wr[k4] = *(const f4*)(wrow + k4 * 4);
      float bias = qb[l * 192 + col];
#pragma unroll
      for (int r = 0; r < 32; r++) {
        float acc = bias;
#pragma unroll
        for (int k4 = 0; k4 < 16; k4++)
          acc = dot4(*(const f4*)&x_s[w][r][k4 * 4], wr[k4], acc);
        s_s[w][r][col] = acc;
      }
    }

    // ---- attention: exact fp32, lane -> (sample, head, dim-half) ----
    {
      const int si = lane >> 3, hh = (lane >> 1) & 3, half = lane & 1;
      const int colb = 16 * hh + 8 * half;
      float kk[4][8], vv[4][8];
#pragma unroll
      for (int u = 0; u < 4; u++)
#pragma unroll
        for (int j = 0; j < 8; j++) {
          kk[u][j] = s_s[w][4 * si + u][64 + colb + j];
          vv[u][j] = s_s[w][4 * si + u][128 + colb + j];
        }
      float oo[4][8];
#pragma unroll
      for (int tq = 0; tq < 4; tq++) {
        float q[8];
#pragma unroll
        for (int j = 0; j < 8; j++) q[j] = s_s[w][4 * si + tq][colb + j];
        float sc[4];
#pragma unroll
        for (int u = 0; u < 4; u++) {
          float d = 0.f;
#pragma unroll
          for (int j = 0; j < 8; j++) d = fmaf(q[j], kk[u][j], d);
          d += __shfl_xor(d, 1);   // join the two 8-dim halves
          sc[u] = d * 0.25f;
        }
        float mx = fmaxf(fmaxf(sc[0], sc[1]), fmaxf(sc[2], sc[3]));
        float p[4], ssum = 0.f;
#pragma unroll
        for (int u = 0; u < 4; u++) { p[u] = expf(sc[u] - mx); ssum += p[u]; }
        float inv = 1.f / ssum;
#pragma unroll
        for (int j = 0; j < 8; j++) {
          float o = 0.f;
#pragma unroll
          for (int u = 0; u < 4; u++) o = fmaf(p[u], vv[u][j], o);
          oo[tq][j] = o * inv;
        }
      }
#pragma unroll
      for (int tq = 0; tq < 4; tq++)
#pragma unroll
        for (int j = 0; j < 8; j++)
          s_s[w][4 * si + tq][colb + j] = oo[tq][j];
    }

    // ---- out-proj + residual + LN1 (per-row, exact) ----
    {
      int col = lane;
      const float* wrow = ow + (long)(l * 64 + col) * 64;
      f4 wr[16];
#pragma unroll
      for (int k4 = 0; k4 < 16; k4++) wr[k4] = *(const f4*)(wrow + k4 * 4);
      float obias = ob[l * 64 + col];
      float gcol = l1g[l * 64 + col], bcol = l1b[l * 64 + col];
#pragma unroll 1
      for (int r = 0; r < 32; r++) {
        float acc = obias;
#pragma unroll
        for (int k4 = 0; k4 < 16; k4++)
          acc = dot4(*(const f4*)&s_s[w][r][k4 * 4], wr[k4], acc);
        float val = acc + x_s[w][r][col];
        float sv = val, qv = val * val;
#pragma unroll
        for (int msk = 1; msk < 64; msk <<= 1) {
          sv += __shfl_xor(sv, msk);
          qv += __shfl_xor(qv, msk);
        }
        float mu = sv * 0.015625f;
        float var = qv * 0.015625f - mu * mu;
        float rs = rsqrtf(var + 1e-5f);
        x_s[w][r][col] = (val - mu) * rs * gcol + bcol;
      }
    }

    // ---- FFN: hidden 256 in 2 halves of 128 (s_s holds one half: cols 0..127) ----
    {
      int col = lane;
      float facc[32];
      float fbias = fb2[l * 64 + col];
#pragma unroll
      for (int r = 0; r < 32; r++) facc[r] = fbias;
#pragma unroll 1
      for (int kh = 0; kh < 2; kh++) {
        // FFN1 half kh: hidden cols kh*128 + (it*64+lane) -> s_s local col
#pragma unroll 1
        for (int it = 0; it < 2; it++) {
          int hcol = kh * 128 + it * 64 + lane;
          const float* wrow = f1w + (long)(l * 256 + hcol) * 64;
          f4 wr[16];
#pragma unroll
          for (int k4 = 0; k4 < 16; k4++) wr[k4] = *(const f4*)(wrow + k4 * 4);
          float bias = fb1[l * 256 + hcol];
#pragma unroll
          for (int r = 0; r < 32; r++) {
            float acc = bias;
#pragma unroll
            for (int k4 = 0; k4 < 16; k4++)
              acc = dot4(*(const f4*)&x_s[w][r][k4 * 4], wr[k4], acc);
            s_s[w][r][it * 64 + lane] = fmaxf(acc, 0.f);
          }
        }
        // FFN2 partial: k in [kh*128, kh*128+128)
        const float* wrow2 = f2w + (long)(l * 64 + col) * 256 + kh * 128;
#pragma unroll 1
        for (int kc = 0; kc < 2; kc++) {
          f4 wr[16];
#pragma unroll
          for (int k4 = 0; k4 < 16; k4++) wr[k4] = *(const f4*)(wrow2 + kc * 64 + k4 * 4);
#pragma unroll
          for (int r = 0; r < 32; r++)
#pragma unroll
            for (int k4 = 0; k4 < 16; k4++)
              facc[r] = dot4(*(const f4*)&s_s[w][r][kc * 64 + k4 * 4], wr[k4], facc[r]);
        }
      }
      // residual + LN2
      float gcol = l2g[l * 64 + col], bcol = l2b[l * 64 + col];
#pragma unroll 1
      for (int r = 0; r < 32; r++) {
        float val = facc[r] + x_s[w][r][col];
        float sv = val, qv = val * val;
#pragma unroll
        for (int msk = 1; msk < 64; msk <<= 1) {
          sv += __shfl_xor(sv, msk);
          qv += __shfl_xor(qv, msk);
        }
        float mu = sv * 0.015625f;
        float var = qv * 0.015625f - mu * mu;
        float rs = rsqrtf(var + 1e-5f);
        x_s[w][r][col] = (val - mu) * rs * gcol + bcol;
      }
    }
  }

  // ---- head: logits from cls rows (token 0 of each of the 8 samples) ----
  {
    int col = lane;
    float w0 = hw[col], w1h = hw[64 + col];
    float hb0 = hb[0], hb1 = hb[1];
#pragma unroll 1
    for (int si = 0; si < 8; si++) {
      float xv = x_s[w][4 * si][col];
      float p0 = xv * w0, p1 = xv * w1h;
#pragma unroll
      for (int msk = 1; msk < 64; msk <<= 1) {
        p0 += __shfl_xor(p0, msk);
        p1 += __shfl_xor(p1, msk);
      }
      if (lane == 0) {
        long sample = (long)(row0 >> 2) + si;
        outp[sample * 2]     = p0 + hb0;
        outp[sample * 2 + 1] = p1 + hb1;
      }
    }
  }
}

// ---------------------------------------------------------------------------
extern "C" void kernel_launch(void* const* d_in, const int* in_sizes, int n_in,
                              void* d_out, int out_size, void* d_ws, size_t ws_size,
                              hipStream_t stream)
{
  const float* x0  = (const float*)d_in[0];
  const float* x1  = (const float*)d_in[1];
  const float* x2  = (const float*)d_in[2];
  const float* gw  = (const float*)d_in[3];
  const float* gb  = (const float*)d_in[4];
  const float* w1  = (const float*)d_in[5];
  const float* eb1 = (const float*)d_in[6];
  const float* w2  = (const float*)d_in[7];
  const float* eb2 = (const float*)d_in[8];
  const float* cls = (const float*)d_in[9];
  const float* pos = (const float*)d_in[10];
  const float* qw  = (const float*)d_in[11];
  const float* qb  = (const float*)d_in[12];
  const float* ow  = (const float*)d_in[13];
  const float* ob  = (const float*)d_in[14];
  const float* l1g = (const float*)d_in[15];
  const float* l1b = (const float*)d_in[16];
  const float* f1w = (const float*)d_in[17];
  const float* fb1 = (const float*)d_in[18];
  const float* f2w = (const float*)d_in[19];
  const float* fb2 = (const float*)d_in[20];
  const float* l2g = (const float*)d_in[21];
  const float* l2b = (const float*)d_in[22];
  const float* hw  = (const float*)d_in[23];
  const float* hb  = (const float*)d_in[24];
  float* xtok = (float*)d_ws;    // [16384][4][64] fp32 tokens

  moe_fp32<<<768, 256, 0, stream>>>(x0, x1, x2, gw, gb, w1, eb1, w2, eb2, cls, pos, xtok);
  former_fp32<<<512, 256, 0, stream>>>(qw, qb, ow, ob, l1g, l1b, f1w, fb1, f2w, fb2,
                                       l2g, l2b, hw, hb, xtok, (float*)d_out);
}